// Round 3
// baseline (522.596 us; speedup 1.0000x reference)
//
#include <hip/hip_runtime.h>
#include <hip/hip_bf16.h>
#include <cmath>

#define B_    32
#define C_    192
#define H_    56
#define W_    56
#define EPS_  1e-5f
#define SCALE_ 0.20412414523193154f  // 24^-0.5

using bf = __hip_bfloat16;
typedef __attribute__((ext_vector_type(8))) short short8;
typedef __attribute__((ext_vector_type(4))) float f32x4;

// ---------------- K0: qkv_w f32 -> bf16 ----------------
__global__ void k_wconv(const float* __restrict__ qkv_w, bf* __restrict__ wbf) {
    int i = blockIdx.x * 256 + threadIdx.x;
    if (i < 576 * 192) wbf[i] = __float2bfloat16(qkv_w[i]);
}

// ---------------- KA: fused bn+gelu (act) + per-pixel LN0 (ptok) ----------------
// one block per (b, h) image row; LDS tile [192][57] f32
__global__ __launch_bounds__(256) void k_act_ptok(
        const float* __restrict__ x,
        const float* __restrict__ bn_g, const float* __restrict__ bn_b,
        const float* __restrict__ bn_m, const float* __restrict__ bn_v,
        const float* __restrict__ ln0g, const float* __restrict__ ln0b,
        bf* __restrict__ act, bf* __restrict__ ptok) {
    __shared__ float tile[C_ * 57];
    __shared__ float mv[W_], rv[W_];
    int b = blockIdx.x / H_, h = blockIdx.x % H_;
    const size_t xbase = ((size_t)b * C_ * H_ + h) * W_;

    for (int f = threadIdx.x; f < C_ * W_; f += 256) {
        int c = f / W_, w = f % W_;
        float v = x[xbase + (size_t)c * (H_ * W_) + w];
        tile[c * 57 + w] = v;
        float xn = (v - bn_m[c]) * rsqrtf(bn_v[c] + EPS_) * bn_g[c] + bn_b[c];
        float ge = 0.5f * xn * (1.0f + erff(xn * 0.70710678118654752f));
        act[xbase + (size_t)c * (H_ * W_) + w] = __float2bfloat16(ge);
    }
    __syncthreads();
    if (threadIdx.x < 224) {
        int p = threadIdx.x >> 2, q = threadIdx.x & 3;
        float S = 0.f, Q = 0.f;
        #pragma unroll 8
        for (int j = 0; j < 48; j++) {
            float v = tile[(q * 48 + j) * 57 + p];
            S += v; Q += v * v;
        }
        S += __shfl_xor(S, 1); Q += __shfl_xor(Q, 1);
        S += __shfl_xor(S, 2); Q += __shfl_xor(Q, 2);
        if (q == 0) {
            float mean = S * (1.f / 192.f);
            float var  = Q * (1.f / 192.f) - mean * mean;
            mv[p] = mean; rv[p] = rsqrtf(var + EPS_);
        }
    }
    __syncthreads();
    const size_t pbase = (((size_t)b * H_ + h) * W_) * C_;
    for (int f = threadIdx.x; f < W_ * C_; f += 256) {
        int p = f / C_, c = f % C_;
        float v = (tile[c * 57 + p] - mv[p]) * rv[p] * ln0g[c] + ln0b[c];
        ptok[pbase + (size_t)p * C_ + c] = __float2bfloat16(v);
    }
}

// ---------------- KB: depthwise 7x7 stride-2 conv on act -> g (f32) ----------------
__global__ __launch_bounds__(256) void k_conv(
        const bf* __restrict__ act, const float* __restrict__ cw,
        const float* __restrict__ cb, float* __restrict__ gbuf) {
    int idx = blockIdx.x * 256 + threadIdx.x;   // exactly 32*192*28*28 threads
    int ow = idx % 28; int t = idx / 28;
    int oh = t % 28; t /= 28;
    int c = t % C_; int b = t / C_;
    float acc = cb[c];
    const float* wr = cw + c * 49;
    #pragma unroll
    for (int kh = 0; kh < 7; kh++) {
        int ih = 2 * oh - 3 + kh;
        if (ih < 0 || ih >= H_) continue;
        const bf* ar = act + (((size_t)b * C_ + c) * H_ + ih) * W_;
        #pragma unroll
        for (int kw = 0; kw < 7; kw++) {
            int iw = 2 * ow - 3 + kw;
            if (iw < 0 || iw >= W_) continue;
            acc += wr[kh * 7 + kw] * __bfloat162float(ar[iw]);
        }
    }
    gbuf[idx] = acc;
}

// ---------------- KC: LN0 over channels of g -> gtok (bf16) ----------------
__global__ __launch_bounds__(256) void k_gtok(
        const float* __restrict__ gbuf,
        const float* __restrict__ ln0g, const float* __restrict__ ln0b,
        bf* __restrict__ gtok) {
    __shared__ float tile[C_ * 29];
    __shared__ float mv[28], rv[28];
    int b = blockIdx.x / 28, oh = blockIdx.x % 28;
    size_t gbase = ((size_t)b * C_ * 784) + (size_t)oh * 28;
    for (int f = threadIdx.x; f < C_ * 28; f += 256) {
        int c = f / 28, w = f % 28;
        tile[c * 29 + w] = gbuf[gbase + (size_t)c * 784 + w];
    }
    __syncthreads();
    if (threadIdx.x < 112) {
        int p = threadIdx.x >> 2, q = threadIdx.x & 3;
        float S = 0.f, Q = 0.f;
        #pragma unroll 8
        for (int j = 0; j < 48; j++) {
            float v = tile[(q * 48 + j) * 29 + p];
            S += v; Q += v * v;
        }
        S += __shfl_xor(S, 1); Q += __shfl_xor(Q, 1);
        S += __shfl_xor(S, 2); Q += __shfl_xor(Q, 2);
        if (q == 0) {
            float mean = S * (1.f / 192.f);
            float var  = Q * (1.f / 192.f) - mean * mean;
            mv[p] = mean; rv[p] = rsqrtf(var + EPS_);
        }
    }
    __syncthreads();
    size_t tbase = ((size_t)b * 784 + (size_t)oh * 28) * C_;
    for (int f = threadIdx.x; f < 28 * C_; f += 256) {
        int p = f / C_, c = f % C_;
        float v = (tile[c * 29 + p] - mv[p]) * rv[p] * ln0g[c] + ln0b[c];
        gtok[tbase + (size_t)p * C_ + c] = __float2bfloat16(v);
    }
}

// ---------------- KD: QKV MFMA GEMM + 5-token attention + LN1 -> out (f32!) ----------------
// 8 windows/block, 256 threads (4 waves). A-tile rows: row = t*8 + win, t=0 guide,
// t=1..4 local (dh,dw), t=5 zero pad.  LDS A swizzled: byte ^= (row&7)<<4.
__global__ __launch_bounds__(256) void k_attn(
        const bf* __restrict__ gtok, const bf* __restrict__ ptok,
        const bf* __restrict__ wbf, const float* __restrict__ qkv_b,
        const float* __restrict__ ln1g, const float* __restrict__ ln1b,
        float* __restrict__ out) {
    __shared__ unsigned char Asm_[48 * 384];
    __shared__ bf q0s[8][192];
    __shared__ bf kvs[2][5][8][192];
    int tid = threadIdx.x;
    int wb0 = blockIdx.x * 8;

    // ---- stage A tile ----
    for (int idx = tid; idx < 48 * 24; idx += 256) {
        int row = idx / 24, j = idx % 24;
        int t = row >> 3, win = row & 7;
        uint4 val = {0u, 0u, 0u, 0u};
        if (t < 5) {
            const unsigned char* src;
            if (t == 0) {
                src = (const unsigned char*)(gtok + (size_t)(wb0 + win) * C_) + j * 16;
            } else {
                int bw = wb0 + win;
                int b = bw / 784; int rr = bw - b * 784;
                int oh = rr / 28, ow = rr - oh * 28;
                int h = 2 * oh + ((t - 1) >> 1), w = 2 * ow + ((t - 1) & 1);
                src = (const unsigned char*)(ptok + (((size_t)b * H_ + h) * W_ + w) * C_) + j * 16;
            }
            val = *(const uint4*)src;
        }
        *(uint4*)(Asm_ + row * 384 + ((j * 16) ^ ((row & 7) << 4))) = val;
    }
    __syncthreads();

    // ---- GEMM: [48,192] x [192,576], n-tiles interleaved across 4 waves ----
    int wid = tid >> 6, lane = tid & 63, lo = lane & 15, hi = lane >> 4;
    int xorv = (lo & 7) << 4;
    for (int nn = 0; nn < 9; nn++) {
        int nt = nn * 4 + wid;
        int col = nt * 16 + lo;
        int mtop = (nt < 12) ? 1 : 3;          // q columns only needed for m-tile 0 (t=0 rows)
        float bias = qkv_b[col];
        f32x4 acc0 = {bias, bias, bias, bias};
        f32x4 acc1 = acc0, acc2 = acc0;
        const unsigned char* bbase = (const unsigned char*)wbf + (size_t)col * 384 + hi * 16;
        #pragma unroll
        for (int ks = 0; ks < 6; ks++) {
            short8 bfrag = *(const short8*)(bbase + ks * 64);
            int kb = ks * 64 + hi * 16;
            short8 a0 = *(const short8*)(Asm_ + lo * 384 + (kb ^ xorv));
            acc0 = __builtin_amdgcn_mfma_f32_16x16x32_bf16(a0, bfrag, acc0, 0, 0, 0);
            if (mtop > 1) {
                short8 a1 = *(const short8*)(Asm_ + (16 + lo) * 384 + (kb ^ xorv));
                acc1 = __builtin_amdgcn_mfma_f32_16x16x32_bf16(a1, bfrag, acc1, 0, 0, 0);
                short8 a2 = *(const short8*)(Asm_ + (32 + lo) * 384 + (kb ^ xorv));
                acc2 = __builtin_amdgcn_mfma_f32_16x16x32_bf16(a2, bfrag, acc2, 0, 0, 0);
            }
        }
        #pragma unroll
        for (int m = 0; m < 3; m++) {
            if (m < mtop) {
                f32x4 a = (m == 0) ? acc0 : ((m == 1) ? acc1 : acc2);
                #pragma unroll
                for (int r = 0; r < 4; r++) {
                    int row = m * 16 + hi * 4 + r;
                    int t = row >> 3, win = row & 7;
                    if (t < 5) {
                        float v = a[r];
                        if (col < 192) {
                            if (t == 0) q0s[win][col] = __float2bfloat16(v);
                        } else if (col < 384) {
                            kvs[0][t][win][col - 192] = __float2bfloat16(v);
                        } else {
                            kvs[1][t][win][col - 384] = __float2bfloat16(v);
                        }
                    }
                }
            }
        }
    }
    __syncthreads();

    // ---- attention + LN1, one thread per (window, head); f32 output ----
    if (tid >= 64) return;
    int win = tid >> 3, hh = tid & 7, base = hh * 24;
    float q[24], o[24];
    #pragma unroll
    for (int d = 0; d < 24; d++) { q[d] = __bfloat162float(q0s[win][base + d]); o[d] = 0.f; }
    float s[5];
    #pragma unroll
    for (int t = 0; t < 5; t++) {
        float a = 0.f;
        #pragma unroll
        for (int d = 0; d < 24; d++) a += q[d] * __bfloat162float(kvs[0][t][win][base + d]);
        s[t] = a * SCALE_;
    }
    float mx = fmaxf(fmaxf(fmaxf(s[0], s[1]), fmaxf(s[2], s[3])), s[4]);
    float sum = 0.f;
    #pragma unroll
    for (int t = 0; t < 5; t++) { s[t] = expf(s[t] - mx); sum += s[t]; }
    float inv = 1.f / sum;
    #pragma unroll
    for (int t = 0; t < 5; t++) {
        float pt = s[t] * inv;
        #pragma unroll
        for (int d = 0; d < 24; d++) o[d] += pt * __bfloat162float(kvs[1][t][win][base + d]);
    }
    float S = 0.f, Q = 0.f;
    #pragma unroll
    for (int d = 0; d < 24; d++) { S += o[d]; Q += o[d] * o[d]; }
    S += __shfl_xor(S, 1); Q += __shfl_xor(Q, 1);
    S += __shfl_xor(S, 2); Q += __shfl_xor(Q, 2);
    S += __shfl_xor(S, 4); Q += __shfl_xor(Q, 4);
    float mean = S * (1.f / 192.f);
    float var  = Q * (1.f / 192.f) - mean * mean;
    float rstd = rsqrtf(var + EPS_);
    size_t ob = (size_t)(wb0 + win) * C_ + base;
    #pragma unroll
    for (int d = 0; d < 24; d++)
        out[ob + d] = (o[d] - mean) * rstd * ln1g[base + d] + ln1b[base + d];
}

// ---------------- launch ----------------
extern "C" void kernel_launch(void* const* d_in, const int* in_sizes, int n_in,
                              void* d_out, int out_size, void* d_ws, size_t ws_size,
                              hipStream_t stream) {
    const float* x       = (const float*)d_in[0];
    const float* bn_g    = (const float*)d_in[1];
    const float* bn_b    = (const float*)d_in[2];
    const float* bn_m    = (const float*)d_in[3];
    const float* bn_v    = (const float*)d_in[4];
    const float* conv_w  = (const float*)d_in[5];
    const float* conv_b  = (const float*)d_in[6];
    const float* qkv_w   = (const float*)d_in[7];
    const float* qkv_b   = (const float*)d_in[8];
    const float* ln0g    = (const float*)d_in[9];
    const float* ln0b    = (const float*)d_in[10];
    const float* ln1g    = (const float*)d_in[11];
    const float* ln1b    = (const float*)d_in[12];

    char* ws = (char*)d_ws;
    // workspace layout (bytes)
    bf*    act  = (bf*)(ws);                       // 38,535,168
    bf*    ptok = (bf*)(ws + 38535168);            // 38,535,168
    bf*    gtok = (bf*)(ws + 77070336);            //  9,633,792
    bf*    wbf  = (bf*)(ws + 86704128);            //    221,184
    float* gbuf = (float*)(ws + 86925312);         // 19,267,584  (total ~106.2 MB)

    k_wconv   <<<dim3(432),   dim3(256), 0, stream>>>(qkv_w, wbf);
    k_act_ptok<<<dim3(B_*H_), dim3(256), 0, stream>>>(x, bn_g, bn_b, bn_m, bn_v,
                                                      ln0g, ln0b, act, ptok);
    k_conv    <<<dim3(18816), dim3(256), 0, stream>>>(act, conv_w, conv_b, gbuf);
    k_gtok    <<<dim3(B_*28), dim3(256), 0, stream>>>(gbuf, ln0g, ln0b, gtok);
    k_attn    <<<dim3(3136),  dim3(256), 0, stream>>>(gtok, ptok, wbf, qkv_b,
                                                      ln1g, ln1b, (float*)d_out);
}

// Round 4
// 304.840 us; speedup vs baseline: 1.7143x; 1.7143x over previous
//
#include <hip/hip_runtime.h>
#include <hip/hip_bf16.h>
#include <cmath>

#define B_    32
#define C_    192
#define H_    56
#define W_    56
#define EPS_  1e-5f
#define SCALE_ 0.20412414523193154f  // 24^-0.5

using bf = __hip_bfloat16;
typedef __attribute__((ext_vector_type(8))) short short8;
typedef __attribute__((ext_vector_type(4))) float f32x4;

// ---------------- K0: qkv_w f32 -> bf16 ----------------
__global__ void k_wconv(const float* __restrict__ qkv_w, bf* __restrict__ wbf) {
    int i = blockIdx.x * 256 + threadIdx.x;
    if (i < 576 * 192) wbf[i] = __float2bfloat16(qkv_w[i]);
}

// ---------------- KA: per-pixel LN0 (ptok) only ----------------
// one block per (b, h) image row; LDS tile [192][57] f32
__global__ __launch_bounds__(256) void k_act_ptok(
        const float* __restrict__ x,
        const float* __restrict__ ln0g, const float* __restrict__ ln0b,
        bf* __restrict__ ptok) {
    __shared__ float tile[C_ * 57];
    __shared__ float mv[W_], rv[W_];
    int b = blockIdx.x / H_, h = blockIdx.x % H_;
    const size_t xbase = ((size_t)b * C_ * H_ + h) * W_;

    for (int f = threadIdx.x; f < C_ * W_; f += 256) {
        int c = f / W_, w = f % W_;
        tile[c * 57 + w] = x[xbase + (size_t)c * (H_ * W_) + w];
    }
    __syncthreads();
    if (threadIdx.x < 224) {
        int p = threadIdx.x >> 2, q = threadIdx.x & 3;
        float S = 0.f, Q = 0.f;
        #pragma unroll 8
        for (int j = 0; j < 48; j++) {
            float v = tile[(q * 48 + j) * 57 + p];
            S += v; Q += v * v;
        }
        S += __shfl_xor(S, 1); Q += __shfl_xor(Q, 1);
        S += __shfl_xor(S, 2); Q += __shfl_xor(Q, 2);
        if (q == 0) {
            float mean = S * (1.f / 192.f);
            float var  = Q * (1.f / 192.f) - mean * mean;
            mv[p] = mean; rv[p] = rsqrtf(var + EPS_);
        }
    }
    __syncthreads();
    const size_t pbase = (((size_t)b * H_ + h) * W_) * C_;
    for (int f = threadIdx.x; f < W_ * C_; f += 256) {
        int p = f / C_, c = f % C_;
        float v = (tile[c * 57 + p] - mv[p]) * rv[p] * ln0g[c] + ln0b[c];
        ptok[pbase + (size_t)p * C_ + c] = __float2bfloat16(v);
    }
}

// ---------------- KB: fused BN+GELU + depthwise 7x7 s2 conv, LDS-staged ----------------
// one block per (b,c) plane; padded 62x63 f32 plane in LDS
__global__ __launch_bounds__(256) void k_conv(
        const float* __restrict__ x,
        const float* __restrict__ bn_g, const float* __restrict__ bn_b,
        const float* __restrict__ bn_m, const float* __restrict__ bn_v,
        const float* __restrict__ cw, const float* __restrict__ cb,
        float* __restrict__ gbuf) {
    __shared__ float pl[62 * 63];
    int tid = threadIdx.x;
    int bc = blockIdx.x;               // b*192 + c
    int c = bc % C_;

    for (int i = tid; i < 62 * 63; i += 256) pl[i] = 0.f;
    __syncthreads();

    float bm = bn_m[c];
    float rs = rsqrtf(bn_v[c] + EPS_) * bn_g[c];
    float bb = bn_b[c];
    const float* xp = x + (size_t)bc * (H_ * W_);
    // 784 float4 loads cover the 56x56 plane (14 per row)
    for (int i = tid; i < 784; i += 256) {
        int row = i / 14, j = i % 14;
        float4 v = *(const float4*)(xp + row * W_ + j * 4);
        float* dst = &pl[(row + 3) * 63 + j * 4 + 3];
        #pragma unroll
        for (int e = 0; e < 4; e++) {
            float xv = (e == 0) ? v.x : (e == 1) ? v.y : (e == 2) ? v.z : v.w;
            float xn = (xv - bm) * rs + bb;
            dst[e] = 0.5f * xn * (1.0f + erff(xn * 0.70710678118654752f));
        }
    }
    __syncthreads();

    float wr[49];
    #pragma unroll
    for (int i = 0; i < 49; i++) wr[i] = cw[c * 49 + i];   // block-uniform -> s_load
    float cbv = cb[c];

    for (int o = tid; o < 784; o += 256) {
        int oh = o / 28, ow = o % 28;
        const float* base = &pl[(2 * oh) * 63 + 2 * ow];
        float acc = cbv;
        #pragma unroll
        for (int kh = 0; kh < 7; kh++) {
            #pragma unroll
            for (int kw = 0; kw < 7; kw++)
                acc += wr[kh * 7 + kw] * base[kh * 63 + kw];
        }
        gbuf[(size_t)bc * 784 + o] = acc;
    }
}

// ---------------- KC: LN0 over channels of g -> gtok (bf16) ----------------
__global__ __launch_bounds__(256) void k_gtok(
        const float* __restrict__ gbuf,
        const float* __restrict__ ln0g, const float* __restrict__ ln0b,
        bf* __restrict__ gtok) {
    __shared__ float tile[C_ * 29];
    __shared__ float mv[28], rv[28];
    int b = blockIdx.x / 28, oh = blockIdx.x % 28;
    size_t gbase = ((size_t)b * C_ * 784) + (size_t)oh * 28;
    for (int f = threadIdx.x; f < C_ * 28; f += 256) {
        int c = f / 28, w = f % 28;
        tile[c * 29 + w] = gbuf[gbase + (size_t)c * 784 + w];
    }
    __syncthreads();
    if (threadIdx.x < 112) {
        int p = threadIdx.x >> 2, q = threadIdx.x & 3;
        float S = 0.f, Q = 0.f;
        #pragma unroll 8
        for (int j = 0; j < 48; j++) {
            float v = tile[(q * 48 + j) * 29 + p];
            S += v; Q += v * v;
        }
        S += __shfl_xor(S, 1); Q += __shfl_xor(Q, 1);
        S += __shfl_xor(S, 2); Q += __shfl_xor(Q, 2);
        if (q == 0) {
            float mean = S * (1.f / 192.f);
            float var  = Q * (1.f / 192.f) - mean * mean;
            mv[p] = mean; rv[p] = rsqrtf(var + EPS_);
        }
    }
    __syncthreads();
    size_t tbase = ((size_t)b * 784 + (size_t)oh * 28) * C_;
    for (int f = threadIdx.x; f < 28 * C_; f += 256) {
        int p = f / C_, c = f % C_;
        float v = (tile[c * 29 + p] - mv[p]) * rv[p] * ln0g[c] + ln0b[c];
        gtok[tbase + (size_t)p * C_ + c] = __float2bfloat16(v);
    }
}

// ---------------- KD: QKV MFMA GEMM + 5-token attention + LN1 -> out (f32) ----------------
__global__ __launch_bounds__(256) void k_attn(
        const bf* __restrict__ gtok, const bf* __restrict__ ptok,
        const bf* __restrict__ wbf, const float* __restrict__ qkv_b,
        const float* __restrict__ ln1g, const float* __restrict__ ln1b,
        float* __restrict__ out) {
    __shared__ unsigned char Asm_[48 * 384];
    __shared__ bf q0s[8][192];
    __shared__ bf kvs[2][5][8][192];
    int tid = threadIdx.x;
    int wb0 = blockIdx.x * 8;

    for (int idx = tid; idx < 48 * 24; idx += 256) {
        int row = idx / 24, j = idx % 24;
        int t = row >> 3, win = row & 7;
        uint4 val = {0u, 0u, 0u, 0u};
        if (t < 5) {
            const unsigned char* src;
            if (t == 0) {
                src = (const unsigned char*)(gtok + (size_t)(wb0 + win) * C_) + j * 16;
            } else {
                int bw = wb0 + win;
                int b = bw / 784; int rr = bw - b * 784;
                int oh = rr / 28, ow = rr - oh * 28;
                int h = 2 * oh + ((t - 1) >> 1), w = 2 * ow + ((t - 1) & 1);
                src = (const unsigned char*)(ptok + (((size_t)b * H_ + h) * W_ + w) * C_) + j * 16;
            }
            val = *(const uint4*)src;
        }
        *(uint4*)(Asm_ + row * 384 + ((j * 16) ^ ((row & 7) << 4))) = val;
    }
    __syncthreads();

    int wid = tid >> 6, lane = tid & 63, lo = lane & 15, hi = lane >> 4;
    int xorv = (lo & 7) << 4;
    for (int nn = 0; nn < 9; nn++) {
        int nt = nn * 4 + wid;
        int col = nt * 16 + lo;
        int mtop = (nt < 12) ? 1 : 3;          // q columns only needed for m-tile 0
        float bias = qkv_b[col];
        f32x4 acc0 = {bias, bias, bias, bias};
        f32x4 acc1 = acc0, acc2 = acc0;
        const unsigned char* bbase = (const unsigned char*)wbf + (size_t)col * 384 + hi * 16;
        #pragma unroll
        for (int ks = 0; ks < 6; ks++) {
            short8 bfrag = *(const short8*)(bbase + ks * 64);
            int kb = ks * 64 + hi * 16;
            short8 a0 = *(const short8*)(Asm_ + lo * 384 + (kb ^ xorv));
            acc0 = __builtin_amdgcn_mfma_f32_16x16x32_bf16(a0, bfrag, acc0, 0, 0, 0);
            if (mtop > 1) {
                short8 a1 = *(const short8*)(Asm_ + (16 + lo) * 384 + (kb ^ xorv));
                acc1 = __builtin_amdgcn_mfma_f32_16x16x32_bf16(a1, bfrag, acc1, 0, 0, 0);
                short8 a2 = *(const short8*)(Asm_ + (32 + lo) * 384 + (kb ^ xorv));
                acc2 = __builtin_amdgcn_mfma_f32_16x16x32_bf16(a2, bfrag, acc2, 0, 0, 0);
            }
        }
        #pragma unroll
        for (int m = 0; m < 3; m++) {
            if (m < mtop) {
                f32x4 a = (m == 0) ? acc0 : ((m == 1) ? acc1 : acc2);
                #pragma unroll
                for (int r = 0; r < 4; r++) {
                    int row = m * 16 + hi * 4 + r;
                    int t = row >> 3, win = row & 7;
                    if (t < 5) {
                        float v = a[r];
                        if (col < 192) {
                            if (t == 0) q0s[win][col] = __float2bfloat16(v);
                        } else if (col < 384) {
                            kvs[0][t][win][col - 192] = __float2bfloat16(v);
                        } else {
                            kvs[1][t][win][col - 384] = __float2bfloat16(v);
                        }
                    }
                }
            }
        }
    }
    __syncthreads();

    if (tid >= 64) return;
    int win = tid >> 3, hh = tid & 7, base = hh * 24;
    float q[24], o[24];
    #pragma unroll
    for (int d = 0; d < 24; d++) { q[d] = __bfloat162float(q0s[win][base + d]); o[d] = 0.f; }
    float s[5];
    #pragma unroll
    for (int t = 0; t < 5; t++) {
        float a = 0.f;
        #pragma unroll
        for (int d = 0; d < 24; d++) a += q[d] * __bfloat162float(kvs[0][t][win][base + d]);
        s[t] = a * SCALE_;
    }
    float mx = fmaxf(fmaxf(fmaxf(s[0], s[1]), fmaxf(s[2], s[3])), s[4]);
    float sum = 0.f;
    #pragma unroll
    for (int t = 0; t < 5; t++) { s[t] = expf(s[t] - mx); sum += s[t]; }
    float inv = 1.f / sum;
    #pragma unroll
    for (int t = 0; t < 5; t++) {
        float pt = s[t] * inv;
        #pragma unroll
        for (int d = 0; d < 24; d++) o[d] += pt * __bfloat162float(kvs[1][t][win][base + d]);
    }
    float S = 0.f, Q = 0.f;
    #pragma unroll
    for (int d = 0; d < 24; d++) { S += o[d]; Q += o[d] * o[d]; }
    S += __shfl_xor(S, 1); Q += __shfl_xor(Q, 1);
    S += __shfl_xor(S, 2); Q += __shfl_xor(Q, 2);
    S += __shfl_xor(S, 4); Q += __shfl_xor(Q, 4);
    float mean = S * (1.f / 192.f);
    float var  = Q * (1.f / 192.f) - mean * mean;
    float rstd = rsqrtf(var + EPS_);
    size_t ob = (size_t)(wb0 + win) * C_ + base;
    #pragma unroll
    for (int d = 0; d < 24; d++)
        out[ob + d] = (o[d] - mean) * rstd * ln1g[base + d] + ln1b[base + d];
}

// ---------------- launch ----------------
extern "C" void kernel_launch(void* const* d_in, const int* in_sizes, int n_in,
                              void* d_out, int out_size, void* d_ws, size_t ws_size,
                              hipStream_t stream) {
    const float* x       = (const float*)d_in[0];
    const float* bn_g    = (const float*)d_in[1];
    const float* bn_b    = (const float*)d_in[2];
    const float* bn_m    = (const float*)d_in[3];
    const float* bn_v    = (const float*)d_in[4];
    const float* conv_w  = (const float*)d_in[5];
    const float* conv_b  = (const float*)d_in[6];
    const float* qkv_w   = (const float*)d_in[7];
    const float* qkv_b   = (const float*)d_in[8];
    const float* ln0g    = (const float*)d_in[9];
    const float* ln0b    = (const float*)d_in[10];
    const float* ln1g    = (const float*)d_in[11];
    const float* ln1b    = (const float*)d_in[12];

    char* ws = (char*)d_ws;
    // workspace layout (bytes)
    bf*    ptok = (bf*)(ws);                       // 38,535,168
    bf*    gtok = (bf*)(ws + 38535168);            //  9,633,792
    bf*    wbf  = (bf*)(ws + 48168960);            //    221,184
    float* gbuf = (float*)(ws + 48390144);         // 19,267,584  (total ~67.7 MB)

    k_wconv   <<<dim3(432),   dim3(256), 0, stream>>>(qkv_w, wbf);
    k_conv    <<<dim3(B_*C_), dim3(256), 0, stream>>>(x, bn_g, bn_b, bn_m, bn_v,
                                                      conv_w, conv_b, gbuf);
    k_act_ptok<<<dim3(B_*H_), dim3(256), 0, stream>>>(x, ln0g, ln0b, ptok);
    k_gtok    <<<dim3(B_*28), dim3(256), 0, stream>>>(gbuf, ln0g, ln0b, gtok);
    k_attn    <<<dim3(3136),  dim3(256), 0, stream>>>(gtok, ptok, wbf, qkv_b,
                                                      ln1g, ln1b, (float*)d_out);
}